// Round 14
// baseline (262.356 us; speedup 1.0000x reference)
//
#include <hip/hip_runtime.h>
#include <hip/hip_bf16.h>

typedef __bf16 bf16x8 __attribute__((ext_vector_type(8)));
typedef __bf16 bf16x4 __attribute__((ext_vector_type(4)));
typedef __bf16 bf16x2 __attribute__((ext_vector_type(2)));
typedef float f32x4 __attribute__((ext_vector_type(4)));

#define HW 4096
#define DIMC 192
#define DH 48
#define HIDC 510
#define LOG2E 1.44269504088896f

// ---------------- merged weight convert: all four fp32 [O][C] -> bf16 [O][Cp] ----------------
__global__ void wcvt4_kernel(const float* __restrict__ qkv_w, const float* __restrict__ proj_w,
                             const float* __restrict__ pin_w, const float* __restrict__ pout_w,
                             __bf16* __restrict__ wb_qkv, __bf16* __restrict__ wb_proj,
                             __bf16* __restrict__ wb_pin, __bf16* __restrict__ wb_pout) {
  int idx = blockIdx.x * 256 + threadIdx.x;
  if (idx < 110592) {                       // qkv 576x192
    wb_qkv[idx] = (__bf16)qkv_w[idx];
  } else if (idx < 147456) {                // proj 192x192
    int i = idx - 110592;
    wb_proj[i] = (__bf16)proj_w[i];
  } else if (idx < 343296) {                // pin 1020x192
    int i = idx - 147456;
    wb_pin[i] = (__bf16)pin_w[i];
  } else if (idx < 441600) {                // pout 192x512 (pad c 510,511)
    int i = idx - 343296;
    int o = i >> 9, c = i & 511;
    wb_pout[i] = (c < HIDC) ? (__bf16)pout_w[o * HIDC + c] : (__bf16)0.f;
  }
}

// ---------------- LN stats: per (b,c) -> sc = rstd*w, sh = b - mean*sc ----------------
__global__ __launch_bounds__(256) void ln_stats_kernel(const float* __restrict__ x, const float* __restrict__ w,
                                                       const float* __restrict__ b, float* __restrict__ sc,
                                                       float* __restrict__ sh) {
  int bc = blockIdx.x;            // b*DIMC + c
  int c = bc % DIMC;
  const float* row = x + (size_t)bc * HW;
  float s = 0.f, s2 = 0.f;
  for (int i = threadIdx.x * 4; i < HW; i += 1024) {
    f32x4 v = *(const f32x4*)&row[i];
    s += (v.x + v.y) + (v.z + v.w);
    s2 = fmaf(v.x, v.x, s2); s2 = fmaf(v.y, v.y, s2);
    s2 = fmaf(v.z, v.z, s2); s2 = fmaf(v.w, v.w, s2);
  }
  __shared__ float red[8];
  for (int off = 32; off; off >>= 1) { s += __shfl_down(s, off, 64); s2 += __shfl_down(s2, off, 64); }
  int wid = threadIdx.x >> 6;
  if ((threadIdx.x & 63) == 0) { red[wid] = s; red[4 + wid] = s2; }
  __syncthreads();
  if (threadIdx.x == 0) {
    s = red[0] + red[1] + red[2] + red[3];
    s2 = red[4] + red[5] + red[6] + red[7];
    float mean = s * (1.f / HW);
    float var = s2 * (1.f / HW) - mean * mean;
    float rstd = rsqrtf(var + 1e-6f);
    float scv = rstd * w[c];
    sc[bc] = scv;
    sh[bc] = b[c] - mean * scv;
  }
}

// ---------------- LN apply + transpose-convert: fp32 [b][192][n] -> bf16 Xt[(b*4096+n)][192] ----------------
__global__ __launch_bounds__(256) void ln_apply_t_kernel(const float* __restrict__ x, const float* __restrict__ sc,
                                                         const float* __restrict__ sh, __bf16* __restrict__ Xt) {
  int n0 = blockIdx.x * 64, c0 = blockIdx.y * 32, b = blockIdx.z;
  int t = threadIdx.x;
  int n = t & 63, cs = c0 + (t >> 6) * 8;
  __bf16 ob[8];
#pragma unroll
  for (int cc = 0; cc < 8; ++cc) {
    int c = cs + cc;
    float v = fmaf(x[((size_t)(b * DIMC + c)) * HW + n0 + n], sc[b * DIMC + c], sh[b * DIMC + c]);
    ob[cc] = (__bf16)v;
  }
  *(bf16x8*)&Xt[((size_t)((b << 12) + n0 + n)) * DIMC + cs] = *(bf16x8*)ob;
}

// ---------------- bf16 MFMA GEMM, K-step 64 ----------------
// mode 0: fp32 out; 1: bf16 out; 2: fp32 out + fp32 residual;
// mode 3: like 2 but B is bf16 [b][510][n] (gate) transposed+padded on the fly (Cs must be 512);
// mode 4: like 2 but B comes from attention split partials Opart (fused merge; Cs must be 192;
//         Bt is the float* Opart with per-block layout O[c 48][n 64] + l[64] @3072, 2 chunks).
__global__ __launch_bounds__(256) void gemm_kernel(const __bf16* __restrict__ A, const __bf16* __restrict__ Bt,
                                                   const float* __restrict__ bias, const float* __restrict__ res,
                                                   float* __restrict__ outf, __bf16* __restrict__ outb,
                                                   int O, int Cs, int mode) {
  __shared__ __align__(16) __bf16 Asub[64 * 72];
  __shared__ __align__(16) __bf16 Bsub[128 * 72];
  __shared__ float linvS[512];
  const int t = threadIdx.x;
  const int lane = t & 63, wv = t >> 6;
  const int q4 = lane >> 4, l16 = lane & 15;
  int o0 = blockIdx.y * 64;
  if (o0 + 64 > O) o0 = O - 64;
  const int ntot0 = blockIdx.x * 128;
  const int b = ntot0 >> 12;
  const int n_in_b0 = ntot0 & 4095;

  if (mode == 4) {
    // stage linv[h][n128]: 4 heads x 128 n, summed over 2 split-K chunks
    const float* pt = (const float*)Bt;
#pragma unroll
    for (int j = 0; j < 2; ++j) {
      int idx = t + 256 * j;               // 0..511
      int h = idx >> 7, nl128 = idx & 127;
      int ntg = (b * 4 + h) * 64 + (n_in_b0 >> 6) + (nl128 >> 6);
      float s = pt[(size_t)ntg * 3136 + 3072 + (nl128 & 63)]
              + pt[(size_t)(512 + ntg) * 3136 + 3072 + (nl128 & 63)];
      linvS[idx] = 1.f / s;
    }
  }

  f32x4 acc[8];
#pragma unroll
  for (int nt = 0; nt < 8; ++nt) acc[nt] = (f32x4){0.f, 0.f, 0.f, 0.f};

  for (int c0 = 0; c0 < Cs; c0 += 64) {
    __syncthreads();
#pragma unroll
    for (int j = 0; j < 2; ++j) {           // A: 64 rows x 64 c
      int id = t + 256 * j;
      *(bf16x8*)&Asub[(id >> 3) * 72 + (id & 7) * 8] =
          *(const bf16x8*)&A[((size_t)(o0 + (id >> 3))) * Cs + c0 + (id & 7) * 8];
    }
    if (mode == 3) {
      // transposing stage from gate [b][510][n]: thread t covers c-row (t>>2), 32-n segment (t&3)
      int cr = t >> 2, seg = t & 3;
      int cg = c0 + cr;
      __bf16 tmp[32];
      if (cg < HIDC) {
        const __bf16* gp = Bt + ((size_t)(b * HIDC + cg)) * HW + n_in_b0 + seg * 32;
#pragma unroll
        for (int j = 0; j < 4; ++j) *(bf16x8*)&tmp[8 * j] = *(const bf16x8*)&gp[8 * j];
      } else {
#pragma unroll
        for (int k = 0; k < 32; ++k) tmp[k] = (__bf16)0.f;
      }
#pragma unroll
      for (int k = 0; k < 32; ++k) Bsub[(seg * 32 + k) * 72 + cr] = tmp[k];
    } else if (mode == 4) {
      // fused attn merge: B[n][c] = (chunk0 + chunk1)(Opart[c][n]) * linv[h][n]
      const float* pt = (const float*)Bt;
      int cr = t >> 2, seg = t & 3;
      int c = c0 + cr;                     // < 192
      int h = c / 48, cin = c - h * 48;
      int ntg = (b * 4 + h) * 64 + (n_in_b0 >> 6) + (seg >> 1);
      size_t base0 = (size_t)ntg * 3136 + (size_t)cin * 64 + (seg & 1) * 32;
      size_t base1 = base0 + (size_t)512 * 3136;
      int n128 = seg * 32;
      __bf16 tmp[32];
#pragma unroll
      for (int k = 0; k < 8; ++k) {
        f32x4 v0 = *(const f32x4*)&pt[base0 + 4 * k];
        f32x4 v1 = *(const f32x4*)&pt[base1 + 4 * k];
#pragma unroll
        for (int e = 0; e < 4; ++e)
          tmp[4 * k + e] = (__bf16)((v0[e] + v1[e]) * linvS[h * 128 + n128 + 4 * k + e]);
      }
#pragma unroll
      for (int k = 0; k < 32; ++k) Bsub[(n128 + k) * 72 + cr] = tmp[k];
    } else {
#pragma unroll
      for (int j = 0; j < 4; ++j) {         // B: 128 rows x 64 c from [n][c] layout
        int id = t + 256 * j;
        *(bf16x8*)&Bsub[(id >> 3) * 72 + (id & 7) * 8] =
            *(const bf16x8*)&Bt[((size_t)(ntot0 + (id >> 3))) * Cs + c0 + (id & 7) * 8];
      }
    }
    __syncthreads();
#pragma unroll
    for (int ks = 0; ks < 2; ++ks) {
      bf16x8 af = *(const bf16x8*)&Asub[(16 * wv + l16) * 72 + 32 * ks + 8 * q4];
#pragma unroll
      for (int nt = 0; nt < 8; ++nt) {
        bf16x8 bfr = *(const bf16x8*)&Bsub[(16 * nt + l16) * 72 + 32 * ks + 8 * q4];
        acc[nt] = __builtin_amdgcn_mfma_f32_16x16x32_bf16(af, bfr, acc[nt], 0, 0, 0);
      }
    }
  }

  float bvals[4];
#pragma unroll
  for (int r = 0; r < 4; ++r) bvals[r] = bias[o0 + 16 * wv + 4 * q4 + r];
#pragma unroll
  for (int nt = 0; nt < 8; ++nt) {
    int n_in_b = n_in_b0 + 16 * nt + l16;
#pragma unroll
    for (int r = 0; r < 4; ++r) {
      int o = o0 + 16 * wv + 4 * q4 + r;
      size_t addr = ((size_t)(b * O + o)) * HW + n_in_b;
      float v = acc[nt][r] + bvals[r];
      if (mode >= 2) { outf[addr] = v + res[addr]; }
      else if (mode == 0) { outf[addr] = v; }
      else { outb[addr] = (__bf16)v; }
    }
  }
}

// ---------------- depthwise 3x3 on bf16 qkv; q,k -> qdwb bf16; v -> Vbf bf16 [bh][c][n] ----------------
__global__ __launch_bounds__(256) void dwconv_split_kernel(const __bf16* __restrict__ in, const float* __restrict__ w,
                                                           const float* __restrict__ bias,
                                                           __bf16* __restrict__ qdwb, __bf16* __restrict__ Vbf) {
  int bc = blockIdx.x;
  int b = bc / 576, ch = bc - b * 576;
  __shared__ float tile[66 * 68];
  for (int i = threadIdx.x; i < 66 * 68; i += 256) tile[i] = 0.f;
  __syncthreads();
  const __bf16* p = in + (size_t)bc * HW;
  for (int j = 0; j < 8; ++j) {
    int i = 2 * threadIdx.x + 512 * j;
    bf16x2 v = *(const bf16x2*)&p[i];
    int y = i >> 6, xx = i & 63;
    tile[(y + 1) * 68 + xx + 1] = (float)v.x;
    tile[(y + 1) * 68 + xx + 2] = (float)v.y;
  }
  __syncthreads();
  float w0 = w[ch * 9 + 0], w1 = w[ch * 9 + 1], w2 = w[ch * 9 + 2];
  float w3 = w[ch * 9 + 3], w4 = w[ch * 9 + 4], w5 = w[ch * 9 + 5];
  float w6 = w[ch * 9 + 6], w7 = w[ch * 9 + 7], w8 = w[ch * 9 + 8];
  float bb = bias[ch];
  __bf16* dst;
  if (ch < 384) dst = qdwb + ((size_t)(b * 384 + ch)) * HW;
  else {
    int c = ch - 384, h = c / DH, cc = c - h * DH;
    dst = Vbf + ((size_t)((b * 4 + h) * DH + cc)) * HW;
  }
  for (int j = 0; j < 8; ++j) {
    int i = 2 * threadIdx.x + 512 * j;
    int y = i >> 6, xx = i & 63;
    const float* tt = &tile[y * 68 + xx];
    float a = bb;
    a = fmaf(w0, tt[0], a);   a = fmaf(w1, tt[1], a);   a = fmaf(w2, tt[2], a);
    a = fmaf(w3, tt[68], a);  a = fmaf(w4, tt[69], a);  a = fmaf(w5, tt[70], a);
    a = fmaf(w6, tt[136], a); a = fmaf(w7, tt[137], a); a = fmaf(w8, tt[138], a);
    float a2 = bb;
    a2 = fmaf(w0, tt[1], a2);   a2 = fmaf(w1, tt[2], a2);   a2 = fmaf(w2, tt[3], a2);
    a2 = fmaf(w3, tt[69], a2);  a2 = fmaf(w4, tt[70], a2);  a2 = fmaf(w5, tt[71], a2);
    a2 = fmaf(w6, tt[137], a2); a2 = fmaf(w7, tt[138], a2); a2 = fmaf(w8, tt[139], a2);
    bf16x2 o = { (__bf16)a, (__bf16)a2 };
    *(bf16x2*)&dst[i] = o;
  }
}

// ---------------- GDFN: dw3x3 on bf16 hid ch j and j+510, gelu(a1)*a2 -> bf16 gate (2-wide) ----------------
__global__ __launch_bounds__(256) void gdfn_dw_gate_kernel(const __bf16* __restrict__ hid, const float* __restrict__ w,
                                                           const float* __restrict__ bias, __bf16* __restrict__ gate) {
  int blk = blockIdx.x;           // b*HIDC + j
  int b = blk / HIDC, j = blk - b * HIDC;
  __shared__ float t1[66 * 68];
  __shared__ float t2[66 * 68];
  for (int i = threadIdx.x; i < 66 * 68; i += 256) { t1[i] = 0.f; t2[i] = 0.f; }
  __syncthreads();
  const __bf16* p1 = hid + ((size_t)b * (2 * HIDC) + j) * HW;
  const __bf16* p2 = p1 + (size_t)HIDC * HW;
  for (int jj = 0; jj < 8; ++jj) {
    int i = 2 * threadIdx.x + 512 * jj;
    bf16x2 v1 = *(const bf16x2*)&p1[i];
    bf16x2 v2 = *(const bf16x2*)&p2[i];
    int y = i >> 6, xx = i & 63;
    t1[(y + 1) * 68 + xx + 1] = (float)v1.x;
    t1[(y + 1) * 68 + xx + 2] = (float)v1.y;
    t2[(y + 1) * 68 + xx + 1] = (float)v2.x;
    t2[(y + 1) * 68 + xx + 2] = (float)v2.y;
  }
  __syncthreads();
  int c1 = j, c2 = j + HIDC;
  float a0 = w[c1*9+0], a1w = w[c1*9+1], a2w = w[c1*9+2], a3 = w[c1*9+3], a4 = w[c1*9+4],
        a5 = w[c1*9+5], a6 = w[c1*9+6], a7 = w[c1*9+7], a8 = w[c1*9+8];
  float b0 = w[c2*9+0], b1 = w[c2*9+1], b2 = w[c2*9+2], b3 = w[c2*9+3], b4 = w[c2*9+4],
        b5 = w[c2*9+5], b6 = w[c2*9+6], b7 = w[c2*9+7], b8 = w[c2*9+8];
  float bi1 = bias[c1], bi2 = bias[c2];
  __bf16* op = gate + ((size_t)b * HIDC + j) * HW;
  for (int jj = 0; jj < 8; ++jj) {
    int i = 2 * threadIdx.x + 512 * jj;
    int y = i >> 6, xx = i & 63;
    const float* u = &t1[y * 68 + xx];
    const float* v = &t2[y * 68 + xx];
    float x1 = bi1;
    x1 = fmaf(a0, u[0], x1);   x1 = fmaf(a1w, u[1], x1);  x1 = fmaf(a2w, u[2], x1);
    x1 = fmaf(a3, u[68], x1);  x1 = fmaf(a4, u[69], x1);  x1 = fmaf(a5, u[70], x1);
    x1 = fmaf(a6, u[136], x1); x1 = fmaf(a7, u[137], x1); x1 = fmaf(a8, u[138], x1);
    float x1b = bi1;
    x1b = fmaf(a0, u[1], x1b);   x1b = fmaf(a1w, u[2], x1b);  x1b = fmaf(a2w, u[3], x1b);
    x1b = fmaf(a3, u[69], x1b);  x1b = fmaf(a4, u[70], x1b);  x1b = fmaf(a5, u[71], x1b);
    x1b = fmaf(a6, u[137], x1b); x1b = fmaf(a7, u[138], x1b); x1b = fmaf(a8, u[139], x1b);
    float x2 = bi2;
    x2 = fmaf(b0, v[0], x2);   x2 = fmaf(b1, v[1], x2);   x2 = fmaf(b2, v[2], x2);
    x2 = fmaf(b3, v[68], x2);  x2 = fmaf(b4, v[69], x2);  x2 = fmaf(b5, v[70], x2);
    x2 = fmaf(b6, v[136], x2); x2 = fmaf(b7, v[137], x2); x2 = fmaf(b8, v[138], x2);
    float x2b = bi2;
    x2b = fmaf(b0, v[1], x2b);   x2b = fmaf(b1, v[2], x2b);   x2b = fmaf(b2, v[3], x2b);
    x2b = fmaf(b3, v[69], x2b);  x2b = fmaf(b4, v[70], x2b);  x2b = fmaf(b5, v[71], x2b);
    x2b = fmaf(b6, v[137], x2b); x2b = fmaf(b7, v[138], x2b); x2b = fmaf(b8, v[139], x2b);
    float g  = 0.5f * x1  * (1.f + erff(x1  * 0.70710678118654752f));
    float gb = 0.5f * x1b * (1.f + erff(x1b * 0.70710678118654752f));
    bf16x2 o = { (__bf16)(g * x2), (__bf16)(gb * x2b) };
    *(bf16x2*)&op[i] = o;
  }
}

// ---------------- prep (2-wide): normalize q,k; fold temp*log2e into q; emit bf16 [bh][n][64] ----------------
__global__ __launch_bounds__(256) void prep_qk_kernel(const __bf16* __restrict__ qdwb, const float* __restrict__ temp,
                                                      __bf16* __restrict__ Qbf, __bf16* __restrict__ Kbf) {
  int t2 = blockIdx.x * 256 + threadIdx.x;   // 0..16383
  int bh = t2 >> 11;
  int np = (t2 & 2047) * 2;
  int b = bh >> 2, h = bh & 3;
  const __bf16* qp = qdwb + ((size_t)(b * 384 + h * DH)) * HW + np;
  const __bf16* kp = qp + (size_t)192 * HW;
  float tq = temp[h] * LOG2E;

  bf16x2 raw[DH];
  float ss0 = 0.f, ss1 = 0.f;
#pragma unroll
  for (int c = 0; c < DH; ++c) {
    bf16x2 v = *(const bf16x2*)&qp[(size_t)c * HW];
    raw[c] = v;
    float f0 = (float)v.x, f1 = (float)v.y;
    ss0 = fmaf(f0, f0, ss0);
    ss1 = fmaf(f1, f1, ss1);
  }
  float sc0 = tq / fmaxf(sqrtf(ss0), 1e-12f);
  float sc1 = tq / fmaxf(sqrtf(ss1), 1e-12f);
  __bf16 ob0[64], ob1[64];
#pragma unroll
  for (int c = 0; c < DH; ++c) {
    ob0[c] = (__bf16)((float)raw[c].x * sc0);
    ob1[c] = (__bf16)((float)raw[c].y * sc1);
  }
#pragma unroll
  for (int c = DH; c < 64; ++c) { ob0[c] = (__bf16)0.f; ob1[c] = (__bf16)0.f; }
  __bf16* qd = Qbf + ((size_t)(bh << 12) + np) * 64;
#pragma unroll
  for (int ch = 0; ch < 8; ++ch) {
    *(bf16x8*)&qd[ch * 8] = *(bf16x8*)&ob0[ch * 8];
    *(bf16x8*)&qd[64 + ch * 8] = *(bf16x8*)&ob1[ch * 8];
  }

  ss0 = 0.f; ss1 = 0.f;
#pragma unroll
  for (int c = 0; c < DH; ++c) {
    bf16x2 v = *(const bf16x2*)&kp[(size_t)c * HW];
    raw[c] = v;
    float f0 = (float)v.x, f1 = (float)v.y;
    ss0 = fmaf(f0, f0, ss0);
    ss1 = fmaf(f1, f1, ss1);
  }
  sc0 = 1.f / fmaxf(sqrtf(ss0), 1e-12f);
  sc1 = 1.f / fmaxf(sqrtf(ss1), 1e-12f);
#pragma unroll
  for (int c = 0; c < DH; ++c) {
    ob0[c] = (__bf16)((float)raw[c].x * sc0);
    ob1[c] = (__bf16)((float)raw[c].y * sc1);
  }
  __bf16* kd = Kbf + ((size_t)(bh << 12) + np) * 64;
#pragma unroll
  for (int ch = 0; ch < 8; ++ch) {
    *(bf16x8*)&kd[ch * 8] = *(bf16x8*)&ob0[ch * 8];
    *(bf16x8*)&kd[64 + ch * 8] = *(bf16x8*)&ob1[ch * 8];
  }
}

// ---------------- flash attention split-K v4: register-prefetch double buffering; Opart [c][n] ----------------
// grid 1024 = chunk*512 + bh*64 + nt; block 256 (4 waves); 32 m-tiles per chunk.
// Partial per block: O[48 c][64 n] fp32 + l[64] at part[bid*3136].
__global__ __launch_bounds__(256) void attn_split_kernel(const __bf16* __restrict__ Qbf, const __bf16* __restrict__ Kbf,
                                                         const __bf16* __restrict__ Vbf, float* __restrict__ part) {
  __shared__ __align__(16) __bf16 Kt[64 * 72];   // Kt[m][c]  (reused as float Lred[4][64] in epilogue)
  __shared__ __align__(16) __bf16 Vc[48 * 72];   // Vc[c][m]
  __shared__ __align__(16) __bf16 Pl[64 * 72];   // Pl[n][m]
  const int tid = threadIdx.x;
  const int lane = tid & 63;
  const int wv = tid >> 6;
  const int q4 = lane >> 4, l16 = lane & 15;
  const int bid = blockIdx.x;
  const int chunk = bid >> 9, rest = bid & 511;
  const int bh = rest >> 6, nt = rest & 63;
  const int n0 = nt * 64;
  const __bf16* Qg = Qbf + (size_t)bh * HW * 64;
  const __bf16* Kg = Kbf + (size_t)bh * HW * 64;
  const __bf16* Vg = Vbf + (size_t)bh * DH * HW;

  // Q fragments in registers (B-operand of S^T): qf[s][ks] = Q[n0+16s+l16][32ks+8q4 ..+7]
  bf16x8 qf[4][2];
#pragma unroll
  for (int s = 0; s < 4; ++s)
#pragma unroll
    for (int ks = 0; ks < 2; ++ks)
      qf[s][ks] = *(const bf16x8*)&Qg[((size_t)(n0 + 16 * s + l16)) * 64 + 32 * ks + 8 * q4];

  // prefetch registers for K (2 chunks/thread) and V (1.5 chunks/thread)
  bf16x8 kreg[2], vreg[2];
  {
    const int m0 = chunk * 32 * 64;
#pragma unroll
    for (int j = 0; j < 2; ++j) {
      int id = tid + 256 * j;
      kreg[j] = *(const bf16x8*)&Kg[((size_t)(m0 + (id >> 3))) * 64 + (id & 7) * 8];
    }
    vreg[0] = *(const bf16x8*)&Vg[((size_t)(tid >> 3)) * HW + m0 + (tid & 7) * 8];
    if (tid < 128) {
      int i = tid + 256;
      vreg[1] = *(const bf16x8*)&Vg[((size_t)(i >> 3)) * HW + m0 + (i & 7) * 8];
    }
  }

  float lsub[4] = {0.f, 0.f, 0.f, 0.f};
  f32x4 oacc[3];
#pragma unroll
  for (int ct = 0; ct < 3; ++ct) oacc[ct] = (f32x4){0.f, 0.f, 0.f, 0.f};

  const int mt_end = chunk * 32 + 32;
  for (int mt = chunk * 32; mt < mt_end; ++mt) {
    __syncthreads();                     // prior iter's LDS reads (Kt in S, Vc/Pl in PV) complete
    // write prefetched regs -> LDS
#pragma unroll
    for (int j = 0; j < 2; ++j) {
      int id = tid + 256 * j;
      *(bf16x8*)&Kt[(id >> 3) * 72 + (id & 7) * 8] = kreg[j];
    }
    *(bf16x8*)&Vc[(tid >> 3) * 72 + (tid & 7) * 8] = vreg[0];
    if (tid < 128) {
      int i = tid + 256;
      *(bf16x8*)&Vc[(i >> 3) * 72 + (i & 7) * 8] = vreg[1];
    }
    // issue next iteration's global loads (consumed at next iter's LDS-write phase)
    if (mt + 1 < mt_end) {
      const int m1 = (mt + 1) * 64;
#pragma unroll
      for (int j = 0; j < 2; ++j) {
        int id = tid + 256 * j;
        kreg[j] = *(const bf16x8*)&Kg[((size_t)(m1 + (id >> 3))) * 64 + (id & 7) * 8];
      }
      vreg[0] = *(const bf16x8*)&Vg[((size_t)(tid >> 3)) * HW + m1 + (tid & 7) * 8];
      if (tid < 128) {
        int i = tid + 256;
        vreg[1] = *(const bf16x8*)&Vg[((size_t)(i >> 3)) * HW + m1 + (i & 7) * 8];
      }
    }
    __syncthreads();                     // staged tile visible

    // S^T[m][n] = K·Q^T: wave owns m-strip 16wv, all 64 n (4 s-tiles)
    f32x4 sacc[4];
#pragma unroll
    for (int s = 0; s < 4; ++s) sacc[s] = (f32x4){0.f, 0.f, 0.f, 0.f};
#pragma unroll
    for (int ks = 0; ks < 2; ++ks) {
      bf16x8 af = *(const bf16x8*)&Kt[(16 * wv + l16) * 72 + 32 * ks + 8 * q4];
#pragma unroll
      for (int s = 0; s < 4; ++s)
        sacc[s] = __builtin_amdgcn_mfma_f32_16x16x32_bf16(af, qf[s][ks], sacc[s], 0, 0, 0);
    }

    // maxless softmax (log2e pre-folded into Q); packed b64 P writes (m-contig)
#pragma unroll
    for (int s = 0; s < 4; ++s) {
      float p0 = exp2f(sacc[s][0]);
      float p1 = exp2f(sacc[s][1]);
      float p2 = exp2f(sacc[s][2]);
      float p3 = exp2f(sacc[s][3]);
      lsub[s] += (p0 + p1) + (p2 + p3);
      bf16x4 pk = { (__bf16)p0, (__bf16)p1, (__bf16)p2, (__bf16)p3 };
      *(bf16x4*)&Pl[(16 * s + l16) * 72 + 16 * wv + 4 * q4] = pk;
    }
    __syncthreads();                     // Pl visible to all waves

    // O[n][c] += P·V^T: wave owns n-strip 16wv
#pragma unroll
    for (int ks = 0; ks < 2; ++ks) {
      bf16x8 pf = *(const bf16x8*)&Pl[(16 * wv + l16) * 72 + 32 * ks + 8 * q4];
#pragma unroll
      for (int ct = 0; ct < 3; ++ct) {
        bf16x8 vf = *(const bf16x8*)&Vc[(16 * ct + l16) * 72 + 32 * ks + 8 * q4];
        oacc[ct] = __builtin_amdgcn_mfma_f32_16x16x32_bf16(pf, vf, oacc[ct], 0, 0, 0);
      }
    }
  }

  // epilogue: lsub[s] holds partial l for n=16s+l16 over this wave's q4-group m-rows;
  // reduce over q4 groups (xor 16,32), then over waves via LDS (reuse Kt).
  __syncthreads();
  float* Lred = (float*)Kt;
#pragma unroll
  for (int s = 0; s < 4; ++s) {
    float v = lsub[s];
    v += __shfl_xor(v, 16, 64);
    v += __shfl_xor(v, 32, 64);
    if (q4 == 0) Lred[wv * 64 + 16 * s + l16] = v;
  }
  __syncthreads();
  size_t pbase = (size_t)bid * 3136;
  if (tid < 64)
    part[pbase + 3072 + tid] = Lred[tid] + Lred[64 + tid] + Lred[128 + tid] + Lred[192 + tid];
  // O partial in [c][n] layout: oacc[ct][r] is (c = 16ct+l16, n = 16wv+4q4+r) -> f32x4 store
#pragma unroll
  for (int ct = 0; ct < 3; ++ct)
    *(f32x4*)&part[pbase + (size_t)(16 * ct + l16) * 64 + 16 * wv + 4 * q4] = oacc[ct];
}

extern "C" void kernel_launch(void* const* d_in, const int* in_sizes, int n_in,
                              void* d_out, int out_size, void* d_ws, size_t ws_size,
                              hipStream_t stream) {
  const float* x        = (const float*)d_in[0];
  const float* ln1_w    = (const float*)d_in[1];
  const float* ln1_b    = (const float*)d_in[2];
  const float* qkv_w    = (const float*)d_in[3];
  const float* qkv_b    = (const float*)d_in[4];
  const float* qkv_dw_w = (const float*)d_in[5];
  const float* qkv_dw_b = (const float*)d_in[6];
  const float* temperature = (const float*)d_in[7];
  const float* proj_w   = (const float*)d_in[8];
  const float* proj_b   = (const float*)d_in[9];
  const float* ln2_w    = (const float*)d_in[10];
  const float* ln2_b    = (const float*)d_in[11];
  const float* pin_w    = (const float*)d_in[12];
  const float* pin_b    = (const float*)d_in[13];
  const float* gdfn_dw_w = (const float*)d_in[14];
  const float* gdfn_dw_b = (const float*)d_in[15];
  const float* pout_w   = (const float*)d_in[16];
  const float* pout_b   = (const float*)d_in[17];
  float* out = (float*)d_out;
  float* ws = (float*)d_ws;

  // ---- workspace layout (float offsets) ----
  __bf16* wb_qkv  = (__bf16*)(ws + 0);          // 55296 f
  __bf16* wb_proj = (__bf16*)(ws + 55296);      // 18432 f
  __bf16* wb_pin  = (__bf16*)(ws + 73728);      // 97920 f
  __bf16* wb_pout = (__bf16*)(ws + 171648);     // 49152 f
  float* sc1 = ws + 220800;
  float* sh1 = ws + 221184;
  float* sc2 = ws + 221568;
  float* sh2 = ws + 221952;                     // ends 222336
  // region B @222336: Xt1/Xt2 overlap Qbf; Q/K/V bf16
  __bf16* Xt1 = (__bf16*)(ws + 222336);
  __bf16* Xt2 = (__bf16*)(ws + 222336);
  __bf16* Qbf = (__bf16*)(ws + 222336);         // 1,048,576 f
  __bf16* Kbf = (__bf16*)(ws + 1270912);        // 1,048,576 f
  __bf16* Vbf = (__bf16*)(ws + 2319488);        // 786,432 f -> ends 3,105,920
  // region C @3,105,920: qkvb bf16 -> later hid
  __bf16* qkvb   = (__bf16*)(ws + 3105920);
  __bf16* hid    = (__bf16*)(ws + 3105920);     // ends 7,283,840
  // region D @5,465,216: qdwb (dead before attn) then Opart
  __bf16* qdwb  = (__bf16*)(ws + 5465216);
  float*  Opart = ws + 5465216;                 // 1024*3136 = 3,211,264 f -> ends 8,676,480
  __bf16* gate  = (__bf16*)(ws + 7283840);      // 2,088,960 f (phase B, Opart dead)
  // total < 11,887,744 f = 47.6 MB

  wcvt4_kernel<<<1725, 256, 0, stream>>>(qkv_w, proj_w, pin_w, pout_w, wb_qkv, wb_proj, wb_pin, wb_pout);

  // ---- phase A ----
  ln_stats_kernel<<<2 * DIMC, 256, 0, stream>>>(x, ln1_w, ln1_b, sc1, sh1);
  ln_apply_t_kernel<<<dim3(64, 6, 2), 256, 0, stream>>>(x, sc1, sh1, Xt1);
  gemm_kernel<<<dim3(64, 9), 256, 0, stream>>>(wb_qkv, Xt1, qkv_b, nullptr, nullptr, qkvb, 576, 192, 1);
  dwconv_split_kernel<<<1152, 256, 0, stream>>>(qkvb, qkv_dw_w, qkv_dw_b, qdwb, Vbf);
  prep_qk_kernel<<<64, 256, 0, stream>>>(qdwb, temperature, Qbf, Kbf);
  attn_split_kernel<<<1024, 256, 0, stream>>>(Qbf, Kbf, Vbf, Opart);
  gemm_kernel<<<dim3(64, 3), 256, 0, stream>>>(wb_proj, (const __bf16*)Opart, proj_b, x, out, nullptr, 192, 192, 4);

  // ---- phase B ----
  ln_stats_kernel<<<2 * DIMC, 256, 0, stream>>>(out, ln2_w, ln2_b, sc2, sh2);
  ln_apply_t_kernel<<<dim3(64, 6, 2), 256, 0, stream>>>(out, sc2, sh2, Xt2);
  gemm_kernel<<<dim3(64, 16), 256, 0, stream>>>(wb_pin, Xt2, pin_b, nullptr, nullptr, hid, 1020, 192, 1);
  gdfn_dw_gate_kernel<<<2 * HIDC, 256, 0, stream>>>(hid, gdfn_dw_w, gdfn_dw_b, gate);
  gemm_kernel<<<dim3(64, 3), 256, 0, stream>>>(wb_pout, (const __bf16*)gate, pout_b, out, out, nullptr, 192, 512, 3);
}

// Round 15
// 257.062 us; speedup vs baseline: 1.0206x; 1.0206x over previous
//
#include <hip/hip_runtime.h>
#include <hip/hip_bf16.h>

typedef __bf16 bf16x8 __attribute__((ext_vector_type(8)));
typedef __bf16 bf16x4 __attribute__((ext_vector_type(4)));
typedef __bf16 bf16x2 __attribute__((ext_vector_type(2)));
typedef float f32x4 __attribute__((ext_vector_type(4)));

#define HW 4096
#define DIMC 192
#define DH 48
#define HIDC 510
#define LOG2E 1.44269504088896f

// ---------------- merged weight convert: all four fp32 [O][C] -> bf16 [O][Cp] ----------------
__global__ void wcvt4_kernel(const float* __restrict__ qkv_w, const float* __restrict__ proj_w,
                             const float* __restrict__ pin_w, const float* __restrict__ pout_w,
                             __bf16* __restrict__ wb_qkv, __bf16* __restrict__ wb_proj,
                             __bf16* __restrict__ wb_pin, __bf16* __restrict__ wb_pout) {
  int idx = blockIdx.x * 256 + threadIdx.x;
  if (idx < 110592) {                       // qkv 576x192
    wb_qkv[idx] = (__bf16)qkv_w[idx];
  } else if (idx < 147456) {                // proj 192x192
    int i = idx - 110592;
    wb_proj[i] = (__bf16)proj_w[i];
  } else if (idx < 343296) {                // pin 1020x192
    int i = idx - 147456;
    wb_pin[i] = (__bf16)pin_w[i];
  } else if (idx < 441600) {                // pout 192x512 (pad c 510,511)
    int i = idx - 343296;
    int o = i >> 9, c = i & 511;
    wb_pout[i] = (c < HIDC) ? (__bf16)pout_w[o * HIDC + c] : (__bf16)0.f;
  }
}

// ---------------- LN stats: per (b,c) -> sc = rstd*w, sh = b - mean*sc ----------------
__global__ __launch_bounds__(256) void ln_stats_kernel(const float* __restrict__ x, const float* __restrict__ w,
                                                       const float* __restrict__ b, float* __restrict__ sc,
                                                       float* __restrict__ sh) {
  int bc = blockIdx.x;            // b*DIMC + c
  int c = bc % DIMC;
  const float* row = x + (size_t)bc * HW;
  float s = 0.f, s2 = 0.f;
  for (int i = threadIdx.x * 4; i < HW; i += 1024) {
    f32x4 v = *(const f32x4*)&row[i];
    s += (v.x + v.y) + (v.z + v.w);
    s2 = fmaf(v.x, v.x, s2); s2 = fmaf(v.y, v.y, s2);
    s2 = fmaf(v.z, v.z, s2); s2 = fmaf(v.w, v.w, s2);
  }
  __shared__ float red[8];
  for (int off = 32; off; off >>= 1) { s += __shfl_down(s, off, 64); s2 += __shfl_down(s2, off, 64); }
  int wid = threadIdx.x >> 6;
  if ((threadIdx.x & 63) == 0) { red[wid] = s; red[4 + wid] = s2; }
  __syncthreads();
  if (threadIdx.x == 0) {
    s = red[0] + red[1] + red[2] + red[3];
    s2 = red[4] + red[5] + red[6] + red[7];
    float mean = s * (1.f / HW);
    float var = s2 * (1.f / HW) - mean * mean;
    float rstd = rsqrtf(var + 1e-6f);
    float scv = rstd * w[c];
    sc[bc] = scv;
    sh[bc] = b[c] - mean * scv;
  }
}

// ---------------- LN apply + transpose-convert: fp32 [b][192][n] -> bf16 Xt[(b*4096+n)][192] ----------------
__global__ __launch_bounds__(256) void ln_apply_t_kernel(const float* __restrict__ x, const float* __restrict__ sc,
                                                         const float* __restrict__ sh, __bf16* __restrict__ Xt) {
  int n0 = blockIdx.x * 64, c0 = blockIdx.y * 32, b = blockIdx.z;
  int t = threadIdx.x;
  int n = t & 63, cs = c0 + (t >> 6) * 8;
  __bf16 ob[8];
#pragma unroll
  for (int cc = 0; cc < 8; ++cc) {
    int c = cs + cc;
    float v = fmaf(x[((size_t)(b * DIMC + c)) * HW + n0 + n], sc[b * DIMC + c], sh[b * DIMC + c]);
    ob[cc] = (__bf16)v;
  }
  *(bf16x8*)&Xt[((size_t)((b << 12) + n0 + n)) * DIMC + cs] = *(bf16x8*)ob;
}

// ---------------- bf16 MFMA GEMM, K-step 64 ----------------
// mode 0: fp32 out; 1: bf16 out; 2: fp32 out + fp32 residual;
// mode 3: like 2 but B is bf16 [b][510][n] (gate) transposed+padded on the fly (Cs must be 512).
__global__ __launch_bounds__(256) void gemm_kernel(const __bf16* __restrict__ A, const __bf16* __restrict__ Bt,
                                                   const float* __restrict__ bias, const float* __restrict__ res,
                                                   float* __restrict__ outf, __bf16* __restrict__ outb,
                                                   int O, int Cs, int mode) {
  __shared__ __align__(16) __bf16 Asub[64 * 72];
  __shared__ __align__(16) __bf16 Bsub[128 * 72];
  const int t = threadIdx.x;
  const int lane = t & 63, wv = t >> 6;
  const int q4 = lane >> 4, l16 = lane & 15;
  int o0 = blockIdx.y * 64;
  if (o0 + 64 > O) o0 = O - 64;
  const int ntot0 = blockIdx.x * 128;
  const int b = ntot0 >> 12;
  const int n_in_b0 = ntot0 & 4095;

  f32x4 acc[8];
#pragma unroll
  for (int nt = 0; nt < 8; ++nt) acc[nt] = (f32x4){0.f, 0.f, 0.f, 0.f};

  for (int c0 = 0; c0 < Cs; c0 += 64) {
    __syncthreads();
#pragma unroll
    for (int j = 0; j < 2; ++j) {           // A: 64 rows x 64 c
      int id = t + 256 * j;
      *(bf16x8*)&Asub[(id >> 3) * 72 + (id & 7) * 8] =
          *(const bf16x8*)&A[((size_t)(o0 + (id >> 3))) * Cs + c0 + (id & 7) * 8];
    }
    if (mode != 3) {
#pragma unroll
      for (int j = 0; j < 4; ++j) {         // B: 128 rows x 64 c from [n][c] layout
        int id = t + 256 * j;
        *(bf16x8*)&Bsub[(id >> 3) * 72 + (id & 7) * 8] =
            *(const bf16x8*)&Bt[((size_t)(ntot0 + (id >> 3))) * Cs + c0 + (id & 7) * 8];
      }
    } else {
      // transposing stage from gate [b][510][n]: thread t covers c-row (t>>2), 32-n segment (t&3)
      int cr = t >> 2, seg = t & 3;
      int cg = c0 + cr;
      __bf16 tmp[32];
      if (cg < HIDC) {
        const __bf16* gp = Bt + ((size_t)(b * HIDC + cg)) * HW + n_in_b0 + seg * 32;
#pragma unroll
        for (int j = 0; j < 4; ++j) *(bf16x8*)&tmp[8 * j] = *(const bf16x8*)&gp[8 * j];
      } else {
#pragma unroll
        for (int k = 0; k < 32; ++k) tmp[k] = (__bf16)0.f;
      }
#pragma unroll
      for (int k = 0; k < 32; ++k) Bsub[(seg * 32 + k) * 72 + cr] = tmp[k];
    }
    __syncthreads();
#pragma unroll
    for (int ks = 0; ks < 2; ++ks) {
      bf16x8 af = *(const bf16x8*)&Asub[(16 * wv + l16) * 72 + 32 * ks + 8 * q4];
#pragma unroll
      for (int nt = 0; nt < 8; ++nt) {
        bf16x8 bfr = *(const bf16x8*)&Bsub[(16 * nt + l16) * 72 + 32 * ks + 8 * q4];
        acc[nt] = __builtin_amdgcn_mfma_f32_16x16x32_bf16(af, bfr, acc[nt], 0, 0, 0);
      }
    }
  }

  float bvals[4];
#pragma unroll
  for (int r = 0; r < 4; ++r) bvals[r] = bias[o0 + 16 * wv + 4 * q4 + r];
#pragma unroll
  for (int nt = 0; nt < 8; ++nt) {
    int n_in_b = n_in_b0 + 16 * nt + l16;
#pragma unroll
    for (int r = 0; r < 4; ++r) {
      int o = o0 + 16 * wv + 4 * q4 + r;
      size_t addr = ((size_t)(b * O + o)) * HW + n_in_b;
      float v = acc[nt][r] + bvals[r];
      if (mode >= 2) { outf[addr] = v + res[addr]; }
      else if (mode == 0) { outf[addr] = v; }
      else { outb[addr] = (__bf16)v; }
    }
  }
}

// ---------------- depthwise 3x3 on bf16 qkv; q,k -> qdwb bf16; v -> Vbf bf16 [bh][c][n] ----------------
__global__ __launch_bounds__(256) void dwconv_split_kernel(const __bf16* __restrict__ in, const float* __restrict__ w,
                                                           const float* __restrict__ bias,
                                                           __bf16* __restrict__ qdwb, __bf16* __restrict__ Vbf) {
  int bc = blockIdx.x;
  int b = bc / 576, ch = bc - b * 576;
  __shared__ float tile[66 * 68];
  for (int i = threadIdx.x; i < 66 * 68; i += 256) tile[i] = 0.f;
  __syncthreads();
  const __bf16* p = in + (size_t)bc * HW;
  for (int j = 0; j < 8; ++j) {
    int i = 2 * threadIdx.x + 512 * j;
    bf16x2 v = *(const bf16x2*)&p[i];
    int y = i >> 6, xx = i & 63;
    tile[(y + 1) * 68 + xx + 1] = (float)v.x;
    tile[(y + 1) * 68 + xx + 2] = (float)v.y;
  }
  __syncthreads();
  float w0 = w[ch * 9 + 0], w1 = w[ch * 9 + 1], w2 = w[ch * 9 + 2];
  float w3 = w[ch * 9 + 3], w4 = w[ch * 9 + 4], w5 = w[ch * 9 + 5];
  float w6 = w[ch * 9 + 6], w7 = w[ch * 9 + 7], w8 = w[ch * 9 + 8];
  float bb = bias[ch];
  __bf16* dst;
  if (ch < 384) dst = qdwb + ((size_t)(b * 384 + ch)) * HW;
  else {
    int c = ch - 384, h = c / DH, cc = c - h * DH;
    dst = Vbf + ((size_t)((b * 4 + h) * DH + cc)) * HW;
  }
  for (int j = 0; j < 8; ++j) {
    int i = 2 * threadIdx.x + 512 * j;
    int y = i >> 6, xx = i & 63;
    const float* tt = &tile[y * 68 + xx];
    float a = bb;
    a = fmaf(w0, tt[0], a);   a = fmaf(w1, tt[1], a);   a = fmaf(w2, tt[2], a);
    a = fmaf(w3, tt[68], a);  a = fmaf(w4, tt[69], a);  a = fmaf(w5, tt[70], a);
    a = fmaf(w6, tt[136], a); a = fmaf(w7, tt[137], a); a = fmaf(w8, tt[138], a);
    float a2 = bb;
    a2 = fmaf(w0, tt[1], a2);   a2 = fmaf(w1, tt[2], a2);   a2 = fmaf(w2, tt[3], a2);
    a2 = fmaf(w3, tt[69], a2);  a2 = fmaf(w4, tt[70], a2);  a2 = fmaf(w5, tt[71], a2);
    a2 = fmaf(w6, tt[137], a2); a2 = fmaf(w7, tt[138], a2); a2 = fmaf(w8, tt[139], a2);
    bf16x2 o = { (__bf16)a, (__bf16)a2 };
    *(bf16x2*)&dst[i] = o;
  }
}

// ---------------- GDFN: dw3x3 on bf16 hid ch j and j+510, gelu(a1)*a2 -> bf16 gate (2-wide) ----------------
__global__ __launch_bounds__(256) void gdfn_dw_gate_kernel(const __bf16* __restrict__ hid, const float* __restrict__ w,
                                                           const float* __restrict__ bias, __bf16* __restrict__ gate) {
  int blk = blockIdx.x;           // b*HIDC + j
  int b = blk / HIDC, j = blk - b * HIDC;
  __shared__ float t1[66 * 68];
  __shared__ float t2[66 * 68];
  for (int i = threadIdx.x; i < 66 * 68; i += 256) { t1[i] = 0.f; t2[i] = 0.f; }
  __syncthreads();
  const __bf16* p1 = hid + ((size_t)b * (2 * HIDC) + j) * HW;
  const __bf16* p2 = p1 + (size_t)HIDC * HW;
  for (int jj = 0; jj < 8; ++jj) {
    int i = 2 * threadIdx.x + 512 * jj;
    bf16x2 v1 = *(const bf16x2*)&p1[i];
    bf16x2 v2 = *(const bf16x2*)&p2[i];
    int y = i >> 6, xx = i & 63;
    t1[(y + 1) * 68 + xx + 1] = (float)v1.x;
    t1[(y + 1) * 68 + xx + 2] = (float)v1.y;
    t2[(y + 1) * 68 + xx + 1] = (float)v2.x;
    t2[(y + 1) * 68 + xx + 2] = (float)v2.y;
  }
  __syncthreads();
  int c1 = j, c2 = j + HIDC;
  float a0 = w[c1*9+0], a1w = w[c1*9+1], a2w = w[c1*9+2], a3 = w[c1*9+3], a4 = w[c1*9+4],
        a5 = w[c1*9+5], a6 = w[c1*9+6], a7 = w[c1*9+7], a8 = w[c1*9+8];
  float b0 = w[c2*9+0], b1 = w[c2*9+1], b2 = w[c2*9+2], b3 = w[c2*9+3], b4 = w[c2*9+4],
        b5 = w[c2*9+5], b6 = w[c2*9+6], b7 = w[c2*9+7], b8 = w[c2*9+8];
  float bi1 = bias[c1], bi2 = bias[c2];
  __bf16* op = gate + ((size_t)b * HIDC + j) * HW;
  for (int jj = 0; jj < 8; ++jj) {
    int i = 2 * threadIdx.x + 512 * jj;
    int y = i >> 6, xx = i & 63;
    const float* u = &t1[y * 68 + xx];
    const float* v = &t2[y * 68 + xx];
    float x1 = bi1;
    x1 = fmaf(a0, u[0], x1);   x1 = fmaf(a1w, u[1], x1);  x1 = fmaf(a2w, u[2], x1);
    x1 = fmaf(a3, u[68], x1);  x1 = fmaf(a4, u[69], x1);  x1 = fmaf(a5, u[70], x1);
    x1 = fmaf(a6, u[136], x1); x1 = fmaf(a7, u[137], x1); x1 = fmaf(a8, u[138], x1);
    float x1b = bi1;
    x1b = fmaf(a0, u[1], x1b);   x1b = fmaf(a1w, u[2], x1b);  x1b = fmaf(a2w, u[3], x1b);
    x1b = fmaf(a3, u[69], x1b);  x1b = fmaf(a4, u[70], x1b);  x1b = fmaf(a5, u[71], x1b);
    x1b = fmaf(a6, u[137], x1b); x1b = fmaf(a7, u[138], x1b); x1b = fmaf(a8, u[139], x1b);
    float x2 = bi2;
    x2 = fmaf(b0, v[0], x2);   x2 = fmaf(b1, v[1], x2);   x2 = fmaf(b2, v[2], x2);
    x2 = fmaf(b3, v[68], x2);  x2 = fmaf(b4, v[69], x2);  x2 = fmaf(b5, v[70], x2);
    x2 = fmaf(b6, v[136], x2); x2 = fmaf(b7, v[137], x2); x2 = fmaf(b8, v[138], x2);
    float x2b = bi2;
    x2b = fmaf(b0, v[1], x2b);   x2b = fmaf(b1, v[2], x2b);   x2b = fmaf(b2, v[3], x2b);
    x2b = fmaf(b3, v[69], x2b);  x2b = fmaf(b4, v[70], x2b);  x2b = fmaf(b5, v[71], x2b);
    x2b = fmaf(b6, v[137], x2b); x2b = fmaf(b7, v[138], x2b); x2b = fmaf(b8, v[139], x2b);
    float g  = 0.5f * x1  * (1.f + erff(x1  * 0.70710678118654752f));
    float gb = 0.5f * x1b * (1.f + erff(x1b * 0.70710678118654752f));
    bf16x2 o = { (__bf16)(g * x2), (__bf16)(gb * x2b) };
    *(bf16x2*)&op[i] = o;
  }
}

// ---------------- prep (2-wide): normalize q,k; fold temp*log2e into q; emit bf16 [bh][n][64] ----------------
__global__ __launch_bounds__(256) void prep_qk_kernel(const __bf16* __restrict__ qdwb, const float* __restrict__ temp,
                                                      __bf16* __restrict__ Qbf, __bf16* __restrict__ Kbf) {
  int t2 = blockIdx.x * 256 + threadIdx.x;   // 0..16383
  int bh = t2 >> 11;
  int np = (t2 & 2047) * 2;
  int b = bh >> 2, h = bh & 3;
  const __bf16* qp = qdwb + ((size_t)(b * 384 + h * DH)) * HW + np;
  const __bf16* kp = qp + (size_t)192 * HW;
  float tq = temp[h] * LOG2E;

  bf16x2 raw[DH];
  float ss0 = 0.f, ss1 = 0.f;
#pragma unroll
  for (int c = 0; c < DH; ++c) {
    bf16x2 v = *(const bf16x2*)&qp[(size_t)c * HW];
    raw[c] = v;
    float f0 = (float)v.x, f1 = (float)v.y;
    ss0 = fmaf(f0, f0, ss0);
    ss1 = fmaf(f1, f1, ss1);
  }
  float sc0 = tq / fmaxf(sqrtf(ss0), 1e-12f);
  float sc1 = tq / fmaxf(sqrtf(ss1), 1e-12f);
  __bf16 ob0[64], ob1[64];
#pragma unroll
  for (int c = 0; c < DH; ++c) {
    ob0[c] = (__bf16)((float)raw[c].x * sc0);
    ob1[c] = (__bf16)((float)raw[c].y * sc1);
  }
#pragma unroll
  for (int c = DH; c < 64; ++c) { ob0[c] = (__bf16)0.f; ob1[c] = (__bf16)0.f; }
  __bf16* qd = Qbf + ((size_t)(bh << 12) + np) * 64;
#pragma unroll
  for (int ch = 0; ch < 8; ++ch) {
    *(bf16x8*)&qd[ch * 8] = *(bf16x8*)&ob0[ch * 8];
    *(bf16x8*)&qd[64 + ch * 8] = *(bf16x8*)&ob1[ch * 8];
  }

  ss0 = 0.f; ss1 = 0.f;
#pragma unroll
  for (int c = 0; c < DH; ++c) {
    bf16x2 v = *(const bf16x2*)&kp[(size_t)c * HW];
    raw[c] = v;
    float f0 = (float)v.x, f1 = (float)v.y;
    ss0 = fmaf(f0, f0, ss0);
    ss1 = fmaf(f1, f1, ss1);
  }
  sc0 = 1.f / fmaxf(sqrtf(ss0), 1e-12f);
  sc1 = 1.f / fmaxf(sqrtf(ss1), 1e-12f);
#pragma unroll
  for (int c = 0; c < DH; ++c) {
    ob0[c] = (__bf16)((float)raw[c].x * sc0);
    ob1[c] = (__bf16)((float)raw[c].y * sc1);
  }
  __bf16* kd = Kbf + ((size_t)(bh << 12) + np) * 64;
#pragma unroll
  for (int ch = 0; ch < 8; ++ch) {
    *(bf16x8*)&kd[ch * 8] = *(bf16x8*)&ob0[ch * 8];
    *(bf16x8*)&kd[64 + ch * 8] = *(bf16x8*)&ob1[ch * 8];
  }
}

// ---------------- flash attention split-K v4b: register-prefetch + split-4 (16 m-tiles/chunk) ----------------
// grid 2048 = chunk*512 + bh*64 + nt; block 256 (4 waves).
// Partial per block: O[64 n][48 c] fp32 + l[64] at part[bid*3136].
__global__ __launch_bounds__(256) void attn_split_kernel(const __bf16* __restrict__ Qbf, const __bf16* __restrict__ Kbf,
                                                         const __bf16* __restrict__ Vbf, float* __restrict__ part) {
  __shared__ __align__(16) __bf16 Kt[64 * 72];   // Kt[m][c]  (reused as float Lred[4][64] in epilogue)
  __shared__ __align__(16) __bf16 Vc[48 * 72];   // Vc[c][m]
  __shared__ __align__(16) __bf16 Pl[64 * 72];   // Pl[n][m]
  const int tid = threadIdx.x;
  const int lane = tid & 63;
  const int wv = tid >> 6;
  const int q4 = lane >> 4, l16 = lane & 15;
  const int bid = blockIdx.x;
  const int chunk = bid >> 9, rest = bid & 511;
  const int bh = rest >> 6, nt = rest & 63;
  const int n0 = nt * 64;
  const __bf16* Qg = Qbf + (size_t)bh * HW * 64;
  const __bf16* Kg = Kbf + (size_t)bh * HW * 64;
  const __bf16* Vg = Vbf + (size_t)bh * DH * HW;

  // Q fragments in registers (B-operand of S^T): qf[s][ks] = Q[n0+16s+l16][32ks+8q4 ..+7]
  bf16x8 qf[4][2];
#pragma unroll
  for (int s = 0; s < 4; ++s)
#pragma unroll
    for (int ks = 0; ks < 2; ++ks)
      qf[s][ks] = *(const bf16x8*)&Qg[((size_t)(n0 + 16 * s + l16)) * 64 + 32 * ks + 8 * q4];

  // prefetch registers for K (2 chunks/thread) and V (1.5 chunks/thread)
  bf16x8 kreg[2], vreg[2];
  {
    const int m0 = chunk * 16 * 64;
#pragma unroll
    for (int j = 0; j < 2; ++j) {
      int id = tid + 256 * j;
      kreg[j] = *(const bf16x8*)&Kg[((size_t)(m0 + (id >> 3))) * 64 + (id & 7) * 8];
    }
    vreg[0] = *(const bf16x8*)&Vg[((size_t)(tid >> 3)) * HW + m0 + (tid & 7) * 8];
    if (tid < 128) {
      int i = tid + 256;
      vreg[1] = *(const bf16x8*)&Vg[((size_t)(i >> 3)) * HW + m0 + (i & 7) * 8];
    }
  }

  float lsub[4] = {0.f, 0.f, 0.f, 0.f};
  f32x4 oacc[3];
#pragma unroll
  for (int ct = 0; ct < 3; ++ct) oacc[ct] = (f32x4){0.f, 0.f, 0.f, 0.f};

  const int mt_end = chunk * 16 + 16;
  for (int mt = chunk * 16; mt < mt_end; ++mt) {
    __syncthreads();                     // prior iter's LDS reads (Kt in S, Vc/Pl in PV) complete
    // write prefetched regs -> LDS
#pragma unroll
    for (int j = 0; j < 2; ++j) {
      int id = tid + 256 * j;
      *(bf16x8*)&Kt[(id >> 3) * 72 + (id & 7) * 8] = kreg[j];
    }
    *(bf16x8*)&Vc[(tid >> 3) * 72 + (tid & 7) * 8] = vreg[0];
    if (tid < 128) {
      int i = tid + 256;
      *(bf16x8*)&Vc[(i >> 3) * 72 + (i & 7) * 8] = vreg[1];
    }
    // issue next iteration's global loads (consumed at next iter's LDS-write phase)
    if (mt + 1 < mt_end) {
      const int m1 = (mt + 1) * 64;
#pragma unroll
      for (int j = 0; j < 2; ++j) {
        int id = tid + 256 * j;
        kreg[j] = *(const bf16x8*)&Kg[((size_t)(m1 + (id >> 3))) * 64 + (id & 7) * 8];
      }
      vreg[0] = *(const bf16x8*)&Vg[((size_t)(tid >> 3)) * HW + m1 + (tid & 7) * 8];
      if (tid < 128) {
        int i = tid + 256;
        vreg[1] = *(const bf16x8*)&Vg[((size_t)(i >> 3)) * HW + m1 + (i & 7) * 8];
      }
    }
    __syncthreads();                     // staged tile visible

    // S^T[m][n] = K·Q^T: wave owns m-strip 16wv, all 64 n (4 s-tiles)
    f32x4 sacc[4];
#pragma unroll
    for (int s = 0; s < 4; ++s) sacc[s] = (f32x4){0.f, 0.f, 0.f, 0.f};
#pragma unroll
    for (int ks = 0; ks < 2; ++ks) {
      bf16x8 af = *(const bf16x8*)&Kt[(16 * wv + l16) * 72 + 32 * ks + 8 * q4];
#pragma unroll
      for (int s = 0; s < 4; ++s)
        sacc[s] = __builtin_amdgcn_mfma_f32_16x16x32_bf16(af, qf[s][ks], sacc[s], 0, 0, 0);
    }

    // maxless softmax (log2e pre-folded into Q); packed b64 P writes (m-contig)
#pragma unroll
    for (int s = 0; s < 4; ++s) {
      float p0 = exp2f(sacc[s][0]);
      float p1 = exp2f(sacc[s][1]);
      float p2 = exp2f(sacc[s][2]);
      float p3 = exp2f(sacc[s][3]);
      lsub[s] += (p0 + p1) + (p2 + p3);
      bf16x4 pk = { (__bf16)p0, (__bf16)p1, (__bf16)p2, (__bf16)p3 };
      *(bf16x4*)&Pl[(16 * s + l16) * 72 + 16 * wv + 4 * q4] = pk;
    }
    __syncthreads();                     // Pl visible to all waves

    // O[n][c] += P·V^T: wave owns n-strip 16wv
#pragma unroll
    for (int ks = 0; ks < 2; ++ks) {
      bf16x8 pf = *(const bf16x8*)&Pl[(16 * wv + l16) * 72 + 32 * ks + 8 * q4];
#pragma unroll
      for (int ct = 0; ct < 3; ++ct) {
        bf16x8 vf = *(const bf16x8*)&Vc[(16 * ct + l16) * 72 + 32 * ks + 8 * q4];
        oacc[ct] = __builtin_amdgcn_mfma_f32_16x16x32_bf16(pf, vf, oacc[ct], 0, 0, 0);
      }
    }
  }

  // epilogue: lsub[s] holds partial l for n=16s+l16 over this wave's q4-group m-rows;
  // reduce over q4 groups (xor 16,32), then over waves via LDS (reuse Kt).
  __syncthreads();
  float* Lred = (float*)Kt;
#pragma unroll
  for (int s = 0; s < 4; ++s) {
    float v = lsub[s];
    v += __shfl_xor(v, 16, 64);
    v += __shfl_xor(v, 32, 64);
    if (q4 == 0) Lred[wv * 64 + 16 * s + l16] = v;
  }
  __syncthreads();
  size_t pbase = (size_t)bid * 3136;
  if (tid < 64)
    part[pbase + 3072 + tid] = Lred[tid] + Lred[64 + tid] + Lred[128 + tid] + Lred[192 + tid];
#pragma unroll
  for (int ct = 0; ct < 3; ++ct)
#pragma unroll
    for (int r = 0; r < 4; ++r) {
      int n = 16 * wv + 4 * q4 + r;
      part[pbase + (size_t)n * 48 + 16 * ct + l16] = oacc[ct][r];
    }
}

// ---------------- merge 4 chunks + normalize -> Xt_att bf16 [(b*4096+n)][192] ----------------
// grid 512 = bh*64 + nt
__global__ __launch_bounds__(256) void attn_merge_kernel(const float* __restrict__ part, __bf16* __restrict__ Xt) {
  const int bid = blockIdx.x;
  const int bh = bid >> 6, nt = bid & 63;
  const int b = bh >> 2, h = bh & 3;
  const int n0 = nt * 64;
  const int t = threadIdx.x;
  __shared__ float linv[64];
  if (t < 64) {
    float s = 0.f;
#pragma unroll
    for (int ch = 0; ch < 4; ++ch) s += part[((size_t)(ch * 512 + bid)) * 3136 + 3072 + t];
    linv[t] = 1.f / s;
  }
  __syncthreads();
#pragma unroll
  for (int j = 0; j < 3; ++j) {
    int id = t + 256 * j;          // 768 f32x4 chunks: n = id/12, c4 = (id%12)*4
    int n = id / 12, cc = (id - n * 12) * 4;
    f32x4 s = (f32x4){0.f, 0.f, 0.f, 0.f};
#pragma unroll
    for (int ch = 0; ch < 4; ++ch) s += *(const f32x4*)&part[((size_t)(ch * 512 + bid)) * 3136 + (size_t)n * 48 + cc];
    float li = linv[n];
    bf16x4 ov = { (__bf16)(s.x * li), (__bf16)(s.y * li), (__bf16)(s.z * li), (__bf16)(s.w * li) };
    *(bf16x4*)&Xt[((size_t)((b << 12) + n0 + n)) * DIMC + h * DH + cc] = ov;
  }
}

extern "C" void kernel_launch(void* const* d_in, const int* in_sizes, int n_in,
                              void* d_out, int out_size, void* d_ws, size_t ws_size,
                              hipStream_t stream) {
  const float* x        = (const float*)d_in[0];
  const float* ln1_w    = (const float*)d_in[1];
  const float* ln1_b    = (const float*)d_in[2];
  const float* qkv_w    = (const float*)d_in[3];
  const float* qkv_b    = (const float*)d_in[4];
  const float* qkv_dw_w = (const float*)d_in[5];
  const float* qkv_dw_b = (const float*)d_in[6];
  const float* temperature = (const float*)d_in[7];
  const float* proj_w   = (const float*)d_in[8];
  const float* proj_b   = (const float*)d_in[9];
  const float* ln2_w    = (const float*)d_in[10];
  const float* ln2_b    = (const float*)d_in[11];
  const float* pin_w    = (const float*)d_in[12];
  const float* pin_b    = (const float*)d_in[13];
  const float* gdfn_dw_w = (const float*)d_in[14];
  const float* gdfn_dw_b = (const float*)d_in[15];
  const float* pout_w   = (const float*)d_in[16];
  const float* pout_b   = (const float*)d_in[17];
  float* out = (float*)d_out;
  float* ws = (float*)d_ws;

  // ---- workspace layout (float offsets) ----
  __bf16* wb_qkv  = (__bf16*)(ws + 0);          // 55296 f
  __bf16* wb_proj = (__bf16*)(ws + 55296);      // 18432 f
  __bf16* wb_pin  = (__bf16*)(ws + 73728);      // 97920 f
  __bf16* wb_pout = (__bf16*)(ws + 171648);     // 49152 f
  float* sc1 = ws + 220800;
  float* sh1 = ws + 221184;
  float* sc2 = ws + 221568;
  float* sh2 = ws + 221952;                     // ends 222336
  // region B @222336: Xt1/Xt2 overlap Qbf; Q/K/V bf16
  __bf16* Xt1 = (__bf16*)(ws + 222336);
  __bf16* Xt2 = (__bf16*)(ws + 222336);
  __bf16* Qbf = (__bf16*)(ws + 222336);         // 1,048,576 f
  __bf16* Kbf = (__bf16*)(ws + 1270912);        // 1,048,576 f
  __bf16* Vbf = (__bf16*)(ws + 2319488);        // 786,432 f -> ends 3,105,920
  // region C @3,105,920: qkvb bf16 -> later Xt_att -> later hid
  __bf16* qkvb   = (__bf16*)(ws + 3105920);
  __bf16* Xt_att = (__bf16*)(ws + 3105920);
  __bf16* hid    = (__bf16*)(ws + 3105920);     // ends 7,283,840
  // region D @5,465,216: qdwb (dead before attn) then Opart (2048 blocks)
  __bf16* qdwb  = (__bf16*)(ws + 5465216);
  float*  Opart = ws + 5465216;                 // 2048*3136 = 6,422,528 f -> ends 11,887,744
  __bf16* gate  = (__bf16*)(ws + 7283840);      // 2,088,960 f (phase B, Opart dead)
  // total 11,887,744 f = 47.6 MB

  wcvt4_kernel<<<1725, 256, 0, stream>>>(qkv_w, proj_w, pin_w, pout_w, wb_qkv, wb_proj, wb_pin, wb_pout);

  // ---- phase A ----
  ln_stats_kernel<<<2 * DIMC, 256, 0, stream>>>(x, ln1_w, ln1_b, sc1, sh1);
  ln_apply_t_kernel<<<dim3(64, 6, 2), 256, 0, stream>>>(x, sc1, sh1, Xt1);
  gemm_kernel<<<dim3(64, 9), 256, 0, stream>>>(wb_qkv, Xt1, qkv_b, nullptr, nullptr, qkvb, 576, 192, 1);
  dwconv_split_kernel<<<1152, 256, 0, stream>>>(qkvb, qkv_dw_w, qkv_dw_b, qdwb, Vbf);
  prep_qk_kernel<<<64, 256, 0, stream>>>(qdwb, temperature, Qbf, Kbf);
  attn_split_kernel<<<2048, 256, 0, stream>>>(Qbf, Kbf, Vbf, Opart);
  attn_merge_kernel<<<512, 256, 0, stream>>>(Opart, Xt_att);
  gemm_kernel<<<dim3(64, 3), 256, 0, stream>>>(wb_proj, Xt_att, proj_b, x, out, nullptr, 192, 192, 2);

  // ---- phase B ----
  ln_stats_kernel<<<2 * DIMC, 256, 0, stream>>>(out, ln2_w, ln2_b, sc2, sh2);
  ln_apply_t_kernel<<<dim3(64, 6, 2), 256, 0, stream>>>(out, sc2, sh2, Xt2);
  gemm_kernel<<<dim3(64, 16), 256, 0, stream>>>(wb_pin, Xt2, pin_b, nullptr, nullptr, hid, 1020, 192, 1);
  gdfn_dw_gate_kernel<<<2 * HIDC, 256, 0, stream>>>(hid, gdfn_dw_w, gdfn_dw_b, gate);
  gemm_kernel<<<dim3(64, 3), 256, 0, stream>>>(wb_pout, (const __bf16*)gate, pout_b, out, out, nullptr, 192, 512, 3);
}